// Round 13
// baseline (117.001 us; speedup 1.0000x reference)
//
#include <hip/hip_runtime.h>

#define NLAT  256
#define NLON  512
#define LMAXX 128
#define MMAXX 128
#define NV    64
#define NBTE  4   // B*T*E = 2*2*1

typedef __attribute__((ext_vector_type(8))) short bf16x8;
typedef __attribute__((ext_vector_type(4))) short bf16x4;
typedef __attribute__((ext_vector_type(4))) float f32x4;

// round-to-nearest-even float -> bf16
__device__ __forceinline__ unsigned int f2bf(float x) {
    union { float f; unsigned int u; } a; a.f = x;
    return (a.u + 0x7fffu + ((a.u >> 16) & 1u)) >> 16;
}

// ---------------------------------------------------------------------------
// init_tsw: twiddle matrix T[256][512] bf16, pre-swizzled into MFMA A-fragment
// order.  T[row][n]: row<128 -> cos(2*pi*row*n/512) (re), row>=128 -> -sin (im).
// Flat: tsw[((ks*16 + mt)*64 + l)*8 + i] = T[mt*16+(l&15)][ks*32+(l>>4)*8+i]
// ---------------------------------------------------------------------------
__global__ __launch_bounds__(256) void init_tsw(unsigned short* __restrict__ tsw) {
    const int gid = blockIdx.x * 256 + threadIdx.x;   // 131072 total
    const int i  = gid & 7;
    const int l  = (gid >> 3) & 63;
    const int mt = (gid >> 9) & 15;
    const int ks = gid >> 13;
    const int row = mt * 16 + (l & 15);
    const int n   = ks * 32 + (l >> 4) * 8 + i;
    const int m   = row & 127;
    float s, c;
    sincosf((6.28318530717958647692f / NLON) * (float)((m * n) & (NLON - 1)), &s, &c);
    const float val = (row < 128) ? c : -s;
    tsw[gid] = (unsigned short)f2bf(val);
}

// ---------------------------------------------------------------------------
// dft_mfma v3: 1 lat-row/block (grid 1024), 4 waves = (m-half, v-half).
// Explicitly software-pipelined: X chunk double-buffer (issue-early/write-late)
// + A-fragment 1-ks-ahead register prefetch. Same accumulation order as v2.
// F[bte][m][lat][cpl*64+v] planar fp32.
// ---------------------------------------------------------------------------
__global__ __launch_bounds__(256) void dft_mfma(const float* __restrict__ data,
                                                const unsigned short* __restrict__ tsw,
                                                float* __restrict__ F) {
    __shared__ unsigned short xs[2][64][136];   // 2 x 17.4 KB
    const int t  = threadIdx.x;
    const int l  = t & 63;
    const int q  = t >> 6;             // wave
    const int mh = q >> 1;             // m half: 0 = re-rows, 1 = im-rows
    const int vh = q & 1;              // v half
    const int row = blockIdx.x;        // bte*NLAT + lat

    f32x4 acc[8][2];
    #pragma unroll
    for (int mt = 0; mt < 8; ++mt)
        #pragma unroll
        for (int vt = 0; vt < 2; ++vt) acc[mt][vt] = (f32x4){0.f, 0.f, 0.f, 0.f};

    const int vv = t & 63;             // staging: v (lane -> coalesced)
    const int ng = t >> 6;             // staging: n subgroup (32 n each)
    const float* Xb = data + ((size_t)row * NLON + ng * 32) * NV + vv;

    float xr[32];
    // prologue: load + stage chunk 0
    #pragma unroll
    for (int g = 0; g < 32; ++g) xr[g] = Xb[(size_t)g * NV];
    #pragma unroll
    for (int g = 0; g < 8; ++g) {
        bf16x4 pk;
        pk.x = (short)f2bf(xr[g * 4 + 0]);
        pk.y = (short)f2bf(xr[g * 4 + 1]);
        pk.z = (short)f2bf(xr[g * 4 + 2]);
        pk.w = (short)f2bf(xr[g * 4 + 3]);
        *(bf16x4*)&xs[0][vv][ng * 32 + g * 4] = pk;
    }
    __syncthreads();

    #pragma unroll
    for (int ch = 0; ch < 4; ++ch) {
        const int cur = ch & 1;
        // issue next-chunk global loads early (latency hides under MFMA below)
        if (ch < 3) {
            const float* Xn = Xb + (size_t)(ch + 1) * 128 * NV;
            #pragma unroll
            for (int g = 0; g < 32; ++g) xr[g] = Xn[(size_t)g * NV];
        }
        // A-pipelined compute on xs[cur]
        {
            const unsigned short* ap0 = tsw + ((size_t)((ch * 4 + 0) * 16 + mh * 8)) * 512 + l * 8;
            bf16x8 aP[8];
            #pragma unroll
            for (int mt = 0; mt < 8; ++mt) aP[mt] = *(const bf16x8*)(ap0 + mt * 512);
            #pragma unroll
            for (int ks = 0; ks < 4; ++ks) {
                bf16x8 aN[8];
                if (ks < 3) {
                    const unsigned short* apn = tsw + ((size_t)((ch * 4 + ks + 1) * 16 + mh * 8)) * 512 + l * 8;
                    #pragma unroll
                    for (int mt = 0; mt < 8; ++mt) aN[mt] = *(const bf16x8*)(apn + mt * 512);
                }
                const bf16x8 b0 = *(const bf16x8*)&xs[cur][vh * 32 + (l & 15)][ks * 32 + (l >> 4) * 8];
                const bf16x8 b1 = *(const bf16x8*)&xs[cur][vh * 32 + 16 + (l & 15)][ks * 32 + (l >> 4) * 8];
                #pragma unroll
                for (int mt = 0; mt < 8; ++mt) {
                    acc[mt][0] = __builtin_amdgcn_mfma_f32_16x16x32_bf16(aP[mt], b0, acc[mt][0], 0, 0, 0);
                    acc[mt][1] = __builtin_amdgcn_mfma_f32_16x16x32_bf16(aP[mt], b1, acc[mt][1], 0, 0, 0);
                }
                if (ks < 3) {
                    #pragma unroll
                    for (int mt = 0; mt < 8; ++mt) aP[mt] = aN[mt];   // renamed by unroll
                }
            }
        }
        // convert & write next chunk into the other buffer
        if (ch < 3) {
            #pragma unroll
            for (int g = 0; g < 8; ++g) {
                bf16x4 pk;
                pk.x = (short)f2bf(xr[g * 4 + 0]);
                pk.y = (short)f2bf(xr[g * 4 + 1]);
                pk.z = (short)f2bf(xr[g * 4 + 2]);
                pk.w = (short)f2bf(xr[g * 4 + 3]);
                *(bf16x4*)&xs[cur ^ 1][vv][ng * 32 + g * 4] = pk;
            }
        }
        __syncthreads();
    }

    // epilogue: D[row = (mh*8+mt)*16 + (l>>4)*4 + j][col = vh*32+vt*16+(l&15)]
    const int bte = row >> 8, lat = row & (NLAT - 1);
    const int g4    = (l >> 4) * 4;
    const int vbase = vh * 32 + (l & 15);
    #pragma unroll
    for (int mt = 0; mt < 8; ++mt) {
        #pragma unroll
        for (int j = 0; j < 4; ++j) {
            const int m = mt * 16 + g4 + j;
            float* dp = F + ((size_t)(bte * MMAXX + m) * NLAT + lat) * (NV * 2) + mh * 64 + vbase;
            dp[0]  = acc[mt][0][j];
            dp[16] = acc[mt][1][j];
        }
    }
}

// ---------------------------------------------------------------------------
// Fallback fp32 DFT (only if ws too small for full-m F) — planar F epilogue.
// ---------------------------------------------------------------------------
template<int MPT>
__global__ __launch_bounds__(256) void dft_lon(const float* __restrict__ data,
                                               float* __restrict__ F,
                                               int m_base, int mch) {
    __shared__ float2 tw[NLON];
    __shared__ float  xs[64 * NV];
    const int row = blockIdx.x;
    const int t   = threadIdx.x;
    const float* __restrict__ X = data + (size_t)row * (NLON * NV);

    for (int i = t; i < NLON; i += 256) {
        float s, c;
        sincosf((6.28318530717958647692f / NLON) * (float)i, &s, &c);
        tw[i] = make_float2(c, -s);
    }
    const int mg = t >> 3, vg = t & 7;
    const int m0 = m_base + mg * MPT;

    float ar[MPT][8], ai[MPT][8];
    #pragma unroll
    for (int j = 0; j < MPT; ++j)
        #pragma unroll
        for (int v = 0; v < 8; ++v) { ar[j][v] = 0.f; ai[j][v] = 0.f; }
    int idx[MPT];
    #pragma unroll
    for (int j = 0; j < MPT; ++j) idx[j] = 0;

    for (int chunk = 0; chunk < NLON / 64; ++chunk) {
        __syncthreads();
        const float4* src = (const float4*)(X + (size_t)chunk * 64 * NV);
        float4*       dst = (float4*)xs;
        #pragma unroll
        for (int j = 0; j < 4; ++j) dst[t + j * 256] = src[t + j * 256];
        __syncthreads();
        for (int n = 0; n < 64; ++n) {
            const float4 x0 = *(const float4*)&xs[n * NV + vg * 8];
            const float4 x1 = *(const float4*)&xs[n * NV + vg * 8 + 4];
            const float xv[8] = {x0.x, x0.y, x0.z, x0.w, x1.x, x1.y, x1.z, x1.w};
            #pragma unroll
            for (int j = 0; j < MPT; ++j) {
                const float2 w = tw[idx[j]];
                idx[j] = (idx[j] + m0 + j) & (NLON - 1);
                #pragma unroll
                for (int v = 0; v < 8; ++v) {
                    ar[j][v] = fmaf(w.x, xv[v], ar[j][v]);
                    ai[j][v] = fmaf(w.y, xv[v], ai[j][v]);
                }
            }
        }
    }
    const int bte = row >> 8, lat = row & (NLAT - 1);
    #pragma unroll
    for (int j = 0; j < MPT; ++j) {
        const int mi = mg * MPT + j;
        if (mi < mch) {
            float* dp = F + ((size_t)(bte * mch + mi) * NLAT + lat) * (NV * 2);
            *(float4*)(dp + vg * 8)          = make_float4(ar[j][0], ar[j][1], ar[j][2], ar[j][3]);
            *(float4*)(dp + vg * 8 + 4)      = make_float4(ar[j][4], ar[j][5], ar[j][6], ar[j][7]);
            *(float4*)(dp + 64 + vg * 8)     = make_float4(ai[j][0], ai[j][1], ai[j][2], ai[j][3]);
            *(float4*)(dp + 64 + vg * 8 + 4) = make_float4(ai[j][4], ai[j][5], ai[j][6], ai[j][7]);
        }
    }
}

// ---------------------------------------------------------------------------
// leg_contract: out[bte][l][m][v][(im,re)] bf16 = sum_k leg[l][m][k]*qw[k]*F
// F PLANAR [k][c*64+v].  grid (mch, NBTE), block 256: 8 l x 8 cols.
// ---------------------------------------------------------------------------
__global__ __launch_bounds__(256) void leg_contract(const float* __restrict__ F,
                                                    const float* __restrict__ leg,
                                                    const float* __restrict__ qw,
                                                    unsigned short* __restrict__ out,
                                                    int m_base, int mch) {
    __shared__ float As[16 * 128];     // [kk][l]
    __shared__ float Fs[16 * 128];     // [kk][c*64+v] planar (direct copy)
    __shared__ float qs[NLAT];
    const int mi  = blockIdx.x;
    const int m   = m_base + mi;
    const int bte = blockIdx.y;
    const int t   = threadIdx.x;
    qs[t] = qw[t];

    const int cg = t & 15;             // cols: re v=4cg..+3 and im v=4cg..+3
    const int lq = t >> 4;             // l = lq*8 .. +7
    const int la = t >> 1;
    const int kh = (t & 1) * 8;

    const float4* Fb4 = (const float4*)(F + (size_t)(bte * mch + mi) * (NLAT * NV * 2));
    float4* As4 = (float4*)As;
    float4* Fs4 = (float4*)Fs;

    float acc[8][8];
    #pragma unroll
    for (int i = 0; i < 8; ++i)
        #pragma unroll
        for (int j = 0; j < 8; ++j) acc[i][j] = 0.f;

    for (int k0 = 0; k0 < NLAT; k0 += 16) {
        __syncthreads();
        {   // A: As[kk][l] = leg[la][m][k0+kk] * qw[k0+kk]
            const float* lp = leg + ((size_t)la * MMAXX + m) * NLAT + k0 + kh;
            const float4 p0 = *(const float4*)lp;
            const float4 p1 = *(const float4*)(lp + 4);
            const float pv[8] = {p0.x, p0.y, p0.z, p0.w, p1.x, p1.y, p1.z, p1.w};
            #pragma unroll
            for (int j = 0; j < 8; ++j)
                As[(kh + j) * 128 + la] = pv[j] * qs[k0 + kh + j];
        }
        #pragma unroll
        for (int j = 0; j < 2; ++j) {  // F stage: direct (already planar)
            const int g = t + j * 256;
            Fs4[g] = Fb4[k0 * 32 + g];
        }
        __syncthreads();
        #pragma unroll 4
        for (int kk = 0; kk < 16; ++kk) {
            const float4 a0 = As4[kk * 32 + lq * 2];
            const float4 a1 = As4[kk * 32 + lq * 2 + 1];
            const float4 f0 = Fs4[kk * 32 + cg];        // re v=4cg..+3
            const float4 f1 = Fs4[kk * 32 + 16 + cg];   // im v=4cg..+3
            const float av[8] = {a0.x, a0.y, a0.z, a0.w, a1.x, a1.y, a1.z, a1.w};
            const float fv[8] = {f0.x, f0.y, f0.z, f0.w, f1.x, f1.y, f1.z, f1.w};
            #pragma unroll
            for (int i = 0; i < 8; ++i)
                #pragma unroll
                for (int j = 0; j < 8; ++j)
                    acc[i][j] = fmaf(av[i], fv[j], acc[i][j]);
        }
    }

    // acc[i][j]: j=0..3 -> re(v=4cg+j), j=4..7 -> im(v=4cg+j-4). Pair = (im,re).
    #pragma unroll
    for (int i = 0; i < 8; ++i) {
        const int l = lq * 8 + i;
        unsigned short* dp = out + ((size_t)(bte * LMAXX + l) * MMAXX + m) * (NV * 2) + cg * 8;
        uint4 pk;
        pk.x = f2bf(acc[i][4]) | (f2bf(acc[i][0]) << 16);
        pk.y = f2bf(acc[i][5]) | (f2bf(acc[i][1]) << 16);
        pk.z = f2bf(acc[i][6]) | (f2bf(acc[i][2]) << 16);
        pk.w = f2bf(acc[i][7]) | (f2bf(acc[i][3]) << 16);
        *(uint4*)dp = pk;
    }
}

extern "C" void kernel_launch(void* const* d_in, const int* in_sizes, int n_in,
                              void* d_out, int out_size, void* d_ws, size_t ws_size,
                              hipStream_t stream) {
    const float* data = (const float*)d_in[0];    // [4][256][512][64] fp32
    const float* leg  = (const float*)d_in[1];    // [128][128][256] fp32
    const float* qw   = (const float*)d_in[2];    // [256] fp32
    unsigned short* out = (unsigned short*)d_out; // bf16 [4][128][128][64][(im,re)]

    unsigned short* tsw = (unsigned short*)d_ws;              // 256 KB
    float* F = (float*)((char*)d_ws + 131072 * sizeof(unsigned short));

    const size_t per_m = (size_t)NBTE * NLAT * NV * 2 * sizeof(float); // 512 KB
    int mch = MMAXX;
    while (mch > 8 && 262144 + per_m * (size_t)mch > ws_size) mch >>= 1;

    if (mch == MMAXX) {
        init_tsw<<<dim3(512), 256, 0, stream>>>(tsw);
        dft_mfma<<<dim3(NBTE * NLAT), 256, 0, stream>>>(data, tsw, F);
        leg_contract<<<dim3(MMAXX, NBTE), 256, 0, stream>>>(F, leg, qw, out, 0, MMAXX);
    } else {
        const int nch = MMAXX / mch;
        for (int c = 0; c < nch; ++c) {
            const int mb = c * mch;
            if (mch == 64)
                dft_lon<2><<<dim3(NBTE * NLAT), 256, 0, stream>>>(data, F, mb, mch);
            else
                dft_lon<1><<<dim3(NBTE * NLAT), 256, 0, stream>>>(data, F, mb, mch);
            leg_contract<<<dim3(mch, NBTE), 256, 0, stream>>>(F, leg, qw, out, mb, mch);
        }
    }
}

// Round 14
// 55.351 us; speedup vs baseline: 2.1138x; 2.1138x over previous
//
#include <hip/hip_runtime.h>

#define NLAT  256
#define NLON  512
#define LMAXX 128
#define MMAXX 128
#define NV    64
#define NBTE  4   // B*T*E = 2*2*1

typedef __attribute__((ext_vector_type(8))) short bf16x8;
typedef __attribute__((ext_vector_type(4))) short bf16x4;
typedef __attribute__((ext_vector_type(4))) float f32x4;

// round-to-nearest-even float -> bf16
__device__ __forceinline__ unsigned int f2bf(float x) {
    union { float f; unsigned int u; } a; a.f = x;
    return (a.u + 0x7fffu + ((a.u >> 16) & 1u)) >> 16;
}

// ---------------------------------------------------------------------------
// init_tsw: twiddle matrix T[256][512] bf16 in MFMA A-fragment order.
// T[row][n]: row<128 -> cos(2*pi*row*n/512), row>=128 -> -sin.
// tsw[((ks*16 + mt)*64 + l)*8 + i] = T[mt*16+(l&15)][ks*32+(l>>4)*8+i]
// ---------------------------------------------------------------------------
__global__ __launch_bounds__(256) void init_tsw(unsigned short* __restrict__ tsw) {
    const int gid = blockIdx.x * 256 + threadIdx.x;   // 131072 total
    const int i  = gid & 7;
    const int l  = (gid >> 3) & 63;
    const int mt = (gid >> 9) & 15;
    const int ks = gid >> 13;
    const int row = mt * 16 + (l & 15);
    const int n   = ks * 32 + (l >> 4) * 8 + i;
    const int m   = row & 127;
    float s, c;
    sincosf((6.28318530717958647692f / NLON) * (float)((m * n) & (NLON - 1)), &s, &c);
    const float val = (row < 128) ? c : -s;
    tsw[gid] = (unsigned short)f2bf(val);
}

// ---------------------------------------------------------------------------
// wt_pack: W[l][k] = leg[l][m][k]*qw[k] in bf16 MFMA A-fragment order, per m.
// wt[((m*8 + ks)*8 + mt)*512 + lane*8 + i] =
//    W[mt*16+(lane&15)][ks*32+(lane>>4)*8+i]
// 524288 threads, one fragment-row (8 elems) each.
// ---------------------------------------------------------------------------
__global__ __launch_bounds__(256) void wt_pack(const float* __restrict__ leg,
                                               const float* __restrict__ qw,
                                               unsigned short* __restrict__ wt) {
    const int gid  = blockIdx.x * 256 + threadIdx.x;  // 524288
    const int lane = gid & 63;
    const int mt   = (gid >> 6) & 7;
    const int ks   = (gid >> 9) & 7;
    const int m    = gid >> 12;
    const int lr   = mt * 16 + (lane & 15);
    const int k0   = ks * 32 + (lane >> 4) * 8;
    const float* lp = leg + ((size_t)lr * MMAXX + m) * NLAT + k0;
    const float4 p0 = *(const float4*)lp;
    const float4 p1 = *(const float4*)(lp + 4);
    const float4 q0 = *(const float4*)(qw + k0);
    const float4 q1 = *(const float4*)(qw + k0 + 4);
    bf16x8 r;
    r[0] = (short)f2bf(p0.x * q0.x);
    r[1] = (short)f2bf(p0.y * q0.y);
    r[2] = (short)f2bf(p0.z * q0.z);
    r[3] = (short)f2bf(p0.w * q0.w);
    r[4] = (short)f2bf(p1.x * q1.x);
    r[5] = (short)f2bf(p1.y * q1.y);
    r[6] = (short)f2bf(p1.z * q1.z);
    r[7] = (short)f2bf(p1.w * q1.w);
    *(bf16x8*)(wt + (size_t)gid * 8) = r;
}

// ---------------------------------------------------------------------------
// dft_mfma v4: 1 lat-row/block (grid 1024), 4 waves = m-quarters (4 mt each,
// all 64 v). 64-n chunks (16 staging loads/thread, kept in flight), dbuf LDS,
// issue-early/write-late. F output BF16 planar [bte][m][lat][cpl*64+v].
// ---------------------------------------------------------------------------
__global__ __launch_bounds__(256, 3) void dft_mfma(const float* __restrict__ data,
                                                   const unsigned short* __restrict__ tsw,
                                                   unsigned short* __restrict__ F) {
    __shared__ unsigned short xs[2][64][72];   // [buf][v][n+pad], 18.4 KB
    const int t = threadIdx.x;
    const int l = t & 63;
    const int q = t >> 6;              // wave = m quarter (mt = q*4 .. q*4+3)
    const int row = blockIdx.x;        // bte*NLAT + lat
    const int vv = t & 63;             // staging: v
    const int ng = t >> 6;             // staging: 16-n subgroup

    f32x4 acc[4][4];
    #pragma unroll
    for (int mt = 0; mt < 4; ++mt)
        #pragma unroll
        for (int vt = 0; vt < 4; ++vt) acc[mt][vt] = (f32x4){0.f, 0.f, 0.f, 0.f};

    const float* Xb = data + (size_t)row * NLON * NV + vv;

    float xr[16];
    // prologue: chunk 0
    #pragma unroll
    for (int g = 0; g < 16; ++g) xr[g] = Xb[(size_t)(ng * 16 + g) * NV];
    #pragma unroll
    for (int g4 = 0; g4 < 4; ++g4) {
        bf16x4 pk;
        pk.x = (short)f2bf(xr[g4 * 4 + 0]);
        pk.y = (short)f2bf(xr[g4 * 4 + 1]);
        pk.z = (short)f2bf(xr[g4 * 4 + 2]);
        pk.w = (short)f2bf(xr[g4 * 4 + 3]);
        *(bf16x4*)&xs[0][vv][ng * 16 + g4 * 4] = pk;
    }
    __syncthreads();

    #pragma unroll
    for (int ch = 0; ch < 8; ++ch) {   // 64-n chunks
        const int cur = ch & 1;
        if (ch < 7) {                  // issue next chunk's loads early
            #pragma unroll
            for (int g = 0; g < 16; ++g)
                xr[g] = Xb[(size_t)((ch + 1) * 64 + ng * 16 + g) * NV];
        }
        #pragma unroll
        for (int ksl = 0; ksl < 2; ++ksl) {
            const int ks = ch * 2 + ksl;
            bf16x8 b[4];
            #pragma unroll
            for (int vt = 0; vt < 4; ++vt)
                b[vt] = *(const bf16x8*)&xs[cur][vt * 16 + (l & 15)][ksl * 32 + (l >> 4) * 8];
            const unsigned short* ap = tsw + ((size_t)ks * 16 + q * 4) * 512 + l * 8;
            #pragma unroll
            for (int mt = 0; mt < 4; ++mt) {
                const bf16x8 a = *(const bf16x8*)(ap + (size_t)mt * 512);
                #pragma unroll
                for (int vt = 0; vt < 4; ++vt)
                    acc[mt][vt] = __builtin_amdgcn_mfma_f32_16x16x32_bf16(a, b[vt], acc[mt][vt], 0, 0, 0);
            }
        }
        if (ch < 7) {                  // convert + write-late into other buffer
            #pragma unroll
            for (int g4 = 0; g4 < 4; ++g4) {
                bf16x4 pk;
                pk.x = (short)f2bf(xr[g4 * 4 + 0]);
                pk.y = (short)f2bf(xr[g4 * 4 + 1]);
                pk.z = (short)f2bf(xr[g4 * 4 + 2]);
                pk.w = (short)f2bf(xr[g4 * 4 + 3]);
                *(bf16x4*)&xs[cur ^ 1][vv][ng * 16 + g4 * 4] = pk;
            }
        }
        __syncthreads();
    }

    // epilogue: D[r256 = (q*4+mt)*16 + (l>>4)*4 + j][col = vt*16 + (l&15)]
    const int bte = row >> 8, lat = row & (NLAT - 1);
    const int g4i = (l >> 4) * 4;
    #pragma unroll
    for (int mt = 0; mt < 4; ++mt) {
        #pragma unroll
        for (int j = 0; j < 4; ++j) {
            const int r256 = (q * 4 + mt) * 16 + g4i + j;
            const int m    = r256 & 127;
            const int cpl  = r256 >> 7;            // 0 = re, 1 = im
            unsigned short* dp = F + ((size_t)(bte * MMAXX + m) * NLAT + lat) * (NV * 2) + cpl * 64;
            #pragma unroll
            for (int vt = 0; vt < 4; ++vt)
                dp[vt * 16 + (l & 15)] = (unsigned short)f2bf(acc[mt][vt][j]);
        }
    }
}

// ---------------------------------------------------------------------------
// leg_mfma: per (bte,m) GEMM  C[128 l][128 c] = W[128 l][256 k] x F[256 k][128 c]
// bf16 MFMA, fp32 accum. A = wt (fragment-packed, global). B staged via LDS
// with octet-rotation swizzle: slot(k,c) = (((k>>3)+(c>>3))&3)*8 + (k&7).
// Output bf16 pairs (im,re) packed in-register -> coalesced u32 stores.
// ---------------------------------------------------------------------------
__global__ __launch_bounds__(256, 2) void leg_mfma(const unsigned short* __restrict__ F,
                                                   const unsigned short* __restrict__ wt,
                                                   unsigned int* __restrict__ outu) {
    __shared__ unsigned short fs[2][128][40];  // [buf][c][k-slots+pad], 20.5 KB
    const int t = threadIdx.x;
    const int l = t & 63;
    const int w = t >> 6;              // wave: m-tiles {2w, 2w+1}
    const int m   = blockIdx.x;
    const int bte = blockIdx.y;
    const unsigned short* Fb = F + (size_t)(bte * MMAXX + m) * NLAT * (NV * 2);
    const unsigned short* wb = wt + (size_t)m * 64 * 512 + l * 8;

    const int kk = t >> 4;             // staging k (0..15; +16 for second half)
    const int c8 = (t & 15) * 8;       // staging c base

    f32x4 acc[2][8];
    #pragma unroll
    for (int i = 0; i < 2; ++i)
        #pragma unroll
        for (int j = 0; j < 8; ++j) acc[i][j] = (f32x4){0.f, 0.f, 0.f, 0.f};

    // prologue: stage k-chunk 0
    {
        const bf16x8 s0 = *(const bf16x8*)(Fb + (size_t)kk * 128 + c8);
        const bf16x8 s1 = *(const bf16x8*)(Fb + (size_t)(16 + kk) * 128 + c8);
        #pragma unroll
        for (int e = 0; e < 8; ++e) {
            const int c = c8 + e;
            fs[0][c][(((kk >> 3) + (c >> 3)) & 3) * 8 + (kk & 7)]        = (unsigned short)s0[e];
            fs[0][c][((((16 + kk) >> 3) + (c >> 3)) & 3) * 8 + (kk & 7)] = (unsigned short)s1[e];
        }
    }
    __syncthreads();

    #pragma unroll
    for (int ks = 0; ks < 8; ++ks) {
        const int cur = ks & 1;
        bf16x8 s0, s1;
        if (ks < 7) {                  // issue next k-chunk loads early
            s0 = *(const bf16x8*)(Fb + ((size_t)(ks + 1) * 32 + kk) * 128 + c8);
            s1 = *(const bf16x8*)(Fb + ((size_t)(ks + 1) * 32 + 16 + kk) * 128 + c8);
        }
        bf16x8 bq[8];
        #pragma unroll
        for (int nt = 0; nt < 8; ++nt) {
            const int c = nt * 16 + (l & 15);
            bq[nt] = *(const bf16x8*)&fs[cur][c][(((l >> 4) + (c >> 3)) & 3) * 8];
        }
        #pragma unroll
        for (int mt2 = 0; mt2 < 2; ++mt2) {
            const bf16x8 a = *(const bf16x8*)(wb + ((size_t)ks * 8 + w * 2 + mt2) * 512);
            #pragma unroll
            for (int nt = 0; nt < 8; ++nt)
                acc[mt2][nt] = __builtin_amdgcn_mfma_f32_16x16x32_bf16(a, bq[nt], acc[mt2][nt], 0, 0, 0);
        }
        if (ks < 7) {                  // write-late into other buffer
            #pragma unroll
            for (int e = 0; e < 8; ++e) {
                const int c = c8 + e;
                fs[cur ^ 1][c][(((kk >> 3) + (c >> 3)) & 3) * 8 + (kk & 7)]        = (unsigned short)s0[e];
                fs[cur ^ 1][c][((((16 + kk) >> 3) + (c >> 3)) & 3) * 8 + (kk & 7)] = (unsigned short)s1[e];
            }
        }
        __syncthreads();
    }

    // epilogue: lane holds (l_out = (w*2+mt2)*16 + (l>>4)*4 + j, c = nt*16+(l&15))
    // c<64 -> re(v=c), c>=64 -> im(v=c-64); pair (im,re) -> u32 = im | re<<16.
    #pragma unroll
    for (int mt2 = 0; mt2 < 2; ++mt2) {
        const int lr = (w * 2 + mt2) * 16 + (l >> 4) * 4;
        #pragma unroll
        for (int j = 0; j < 4; ++j) {
            unsigned int* op = outu + ((size_t)(bte * LMAXX + lr + j) * MMAXX + m) * 64 + (l & 15);
            #pragma unroll
            for (int nt = 0; nt < 4; ++nt)
                op[nt * 16] = f2bf(acc[mt2][nt + 4][j]) | (f2bf(acc[mt2][nt][j]) << 16);
        }
    }
}

extern "C" void kernel_launch(void* const* d_in, const int* in_sizes, int n_in,
                              void* d_out, int out_size, void* d_ws, size_t ws_size,
                              hipStream_t stream) {
    const float* data = (const float*)d_in[0];    // [4][256][512][64] fp32
    const float* leg  = (const float*)d_in[1];    // [128][128][256] fp32
    const float* qw   = (const float*)d_in[2];    // [256] fp32
    unsigned int* outu = (unsigned int*)d_out;    // bf16 [4][128][128][64][(im,re)] as u32 pairs

    // ws layout: tsw 256 KB | wt 8.39 MB | F(bf16) 16.78 MB  (ws >= 67 MB per r10-13)
    unsigned short* tsw = (unsigned short*)d_ws;
    unsigned short* wt  = tsw + 131072;
    unsigned short* F   = wt + (size_t)4194304;

    init_tsw<<<dim3(512),  256, 0, stream>>>(tsw);
    wt_pack <<<dim3(2048), 256, 0, stream>>>(leg, qw, wt);
    dft_mfma<<<dim3(NBTE * NLAT), 256, 0, stream>>>(data, tsw, F);
    leg_mfma<<<dim3(MMAXX, NBTE), 256, 0, stream>>>(F, wt, outu);
}

// Round 16
// 49.796 us; speedup vs baseline: 2.3496x; 1.1116x over previous
//
#include <hip/hip_runtime.h>

#define NLAT  256
#define NLON  512
#define LMAXX 128
#define MMAXX 128
#define NV    64
#define NBTE  4   // B*T*E = 2*2*1

typedef __attribute__((ext_vector_type(8))) short bf16x8;
typedef __attribute__((ext_vector_type(4))) short bf16x4;
typedef __attribute__((ext_vector_type(4))) float f32x4;

// round-to-nearest-even float -> bf16
__device__ __forceinline__ unsigned int f2bf(float x) {
    union { float f; unsigned int u; } a; a.f = x;
    return (a.u + 0x7fffu + ((a.u >> 16) & 1u)) >> 16;
}

// ---------------------------------------------------------------------------
// init_tables (fused): blocks 0..511 build tsw, 512..2559 build wt.
// tsw[((ks*16 + mt)*64 + l)*8 + i] = T[mt*16+(l&15)][ks*32+(l>>4)*8+i]
//   T[row][n]: row<128 -> cos(2*pi*row*n/512), row>=128 -> -sin.
// wt[((m*8 + ks)*8 + mt)*512 + lane*8 + i] = leg*qw fragment-packed per m.
// ---------------------------------------------------------------------------
__global__ __launch_bounds__(256) void init_tables(const float* __restrict__ leg,
                                                   const float* __restrict__ qw,
                                                   unsigned short* __restrict__ tsw,
                                                   unsigned short* __restrict__ wt) {
    const int bid = blockIdx.x;
    const int t   = threadIdx.x;
    if (bid < 512) {
        const int gid = bid * 256 + t;                // 131072
        const int i  = gid & 7;
        const int l  = (gid >> 3) & 63;
        const int mt = (gid >> 9) & 15;
        const int ks = gid >> 13;
        const int row = mt * 16 + (l & 15);
        const int n   = ks * 32 + (l >> 4) * 8 + i;
        const int m   = row & 127;
        float s, c;
        sincosf((6.28318530717958647692f / NLON) * (float)((m * n) & (NLON - 1)), &s, &c);
        tsw[gid] = (unsigned short)f2bf((row < 128) ? c : -s);
    } else {
        const int gid  = (bid - 512) * 256 + t;       // 524288
        const int lane = gid & 63;
        const int mt   = (gid >> 6) & 7;
        const int ks   = (gid >> 9) & 7;
        const int m    = gid >> 12;
        const int lr   = mt * 16 + (lane & 15);
        const int k0   = ks * 32 + (lane >> 4) * 8;
        const float* lp = leg + ((size_t)lr * MMAXX + m) * NLAT + k0;
        const float4 p0 = *(const float4*)lp;
        const float4 p1 = *(const float4*)(lp + 4);
        const float4 q0 = *(const float4*)(qw + k0);
        const float4 q1 = *(const float4*)(qw + k0 + 4);
        bf16x8 r;
        r[0] = (short)f2bf(p0.x * q0.x);
        r[1] = (short)f2bf(p0.y * q0.y);
        r[2] = (short)f2bf(p0.z * q0.z);
        r[3] = (short)f2bf(p0.w * q0.w);
        r[4] = (short)f2bf(p1.x * q1.x);
        r[5] = (short)f2bf(p1.y * q1.y);
        r[6] = (short)f2bf(p1.z * q1.z);
        r[7] = (short)f2bf(p1.w * q1.w);
        *(bf16x8*)(wt + (size_t)gid * 8) = r;
    }
}

// ---------------------------------------------------------------------------
// dft_mfma v4 (r14-proven, reverted): 1 lat-row/block (grid 1024), 4 waves =
// m-quarters (4 mt each, all 64 v). 64-n chunks (16 scalar staging loads per
// thread), dbuf LDS, issue-early/write-late.
// F output BF16 planar [bte][m][lat][cpl*64+v].
// ---------------------------------------------------------------------------
__global__ __launch_bounds__(256, 3) void dft_mfma(const float* __restrict__ data,
                                                   const unsigned short* __restrict__ tsw,
                                                   unsigned short* __restrict__ F) {
    __shared__ unsigned short xs[2][64][72];   // [buf][v][n+pad], 18.4 KB
    const int t = threadIdx.x;
    const int l = t & 63;
    const int q = t >> 6;              // wave = m quarter (mt = q*4 .. q*4+3)
    const int row = blockIdx.x;        // bte*NLAT + lat
    const int vv = t & 63;             // staging: v
    const int ng = t >> 6;             // staging: 16-n subgroup

    f32x4 acc[4][4];
    #pragma unroll
    for (int mt = 0; mt < 4; ++mt)
        #pragma unroll
        for (int vt = 0; vt < 4; ++vt) acc[mt][vt] = (f32x4){0.f, 0.f, 0.f, 0.f};

    const float* Xb = data + (size_t)row * NLON * NV + vv;

    float xr[16];
    // prologue: chunk 0
    #pragma unroll
    for (int g = 0; g < 16; ++g) xr[g] = Xb[(size_t)(ng * 16 + g) * NV];
    #pragma unroll
    for (int g4 = 0; g4 < 4; ++g4) {
        bf16x4 pk;
        pk.x = (short)f2bf(xr[g4 * 4 + 0]);
        pk.y = (short)f2bf(xr[g4 * 4 + 1]);
        pk.z = (short)f2bf(xr[g4 * 4 + 2]);
        pk.w = (short)f2bf(xr[g4 * 4 + 3]);
        *(bf16x4*)&xs[0][vv][ng * 16 + g4 * 4] = pk;
    }
    __syncthreads();

    #pragma unroll
    for (int ch = 0; ch < 8; ++ch) {   // 64-n chunks
        const int cur = ch & 1;
        if (ch < 7) {                  // issue next chunk's loads early
            #pragma unroll
            for (int g = 0; g < 16; ++g)
                xr[g] = Xb[(size_t)((ch + 1) * 64 + ng * 16 + g) * NV];
        }
        #pragma unroll
        for (int ksl = 0; ksl < 2; ++ksl) {
            const int ks = ch * 2 + ksl;
            bf16x8 b[4];
            #pragma unroll
            for (int vt = 0; vt < 4; ++vt)
                b[vt] = *(const bf16x8*)&xs[cur][vt * 16 + (l & 15)][ksl * 32 + (l >> 4) * 8];
            const unsigned short* ap = tsw + ((size_t)ks * 16 + q * 4) * 512 + l * 8;
            #pragma unroll
            for (int mt = 0; mt < 4; ++mt) {
                const bf16x8 a = *(const bf16x8*)(ap + (size_t)mt * 512);
                #pragma unroll
                for (int vt = 0; vt < 4; ++vt)
                    acc[mt][vt] = __builtin_amdgcn_mfma_f32_16x16x32_bf16(a, b[vt], acc[mt][vt], 0, 0, 0);
            }
        }
        if (ch < 7) {                  // convert + write-late into other buffer
            #pragma unroll
            for (int g4 = 0; g4 < 4; ++g4) {
                bf16x4 pk;
                pk.x = (short)f2bf(xr[g4 * 4 + 0]);
                pk.y = (short)f2bf(xr[g4 * 4 + 1]);
                pk.z = (short)f2bf(xr[g4 * 4 + 2]);
                pk.w = (short)f2bf(xr[g4 * 4 + 3]);
                *(bf16x4*)&xs[cur ^ 1][vv][ng * 16 + g4 * 4] = pk;
            }
        }
        __syncthreads();
    }

    // epilogue: D[r256 = (q*4+mt)*16 + (l>>4)*4 + j][col = vt*16 + (l&15)]
    const int bte = row >> 8, lat = row & (NLAT - 1);
    const int g4i = (l >> 4) * 4;
    #pragma unroll
    for (int mt = 0; mt < 4; ++mt) {
        #pragma unroll
        for (int j = 0; j < 4; ++j) {
            const int r256 = (q * 4 + mt) * 16 + g4i + j;
            const int m    = r256 & 127;
            const int cpl  = r256 >> 7;            // 0 = re, 1 = im
            unsigned short* dp = F + ((size_t)(bte * MMAXX + m) * NLAT + lat) * (NV * 2) + cpl * 64;
            #pragma unroll
            for (int vt = 0; vt < 4; ++vt)
                dp[vt * 16 + (l & 15)] = (unsigned short)f2bf(acc[mt][vt][j]);
        }
    }
}

// ---------------------------------------------------------------------------
// leg_mfma: per (bte,m) GEMM  C[128 l][128 c] = W[128 l][256 k] x F[256 k][128 c]
// bf16 MFMA, fp32 accum. XCD-swizzled block order (16 consecutive m per XCD ->
// wt L2-resident). Waves whose 32 l-rows are all < m skip compute (W zero
// triangle) -- acc stays 0, stores unchanged.
// ---------------------------------------------------------------------------
__global__ __launch_bounds__(256, 2) void leg_mfma(const unsigned short* __restrict__ F,
                                                   const unsigned short* __restrict__ wt,
                                                   unsigned int* __restrict__ outu) {
    __shared__ unsigned short fs[2][128][40];  // [buf][c][k-slots+pad], 20.5 KB
    const int bid = blockIdx.x;                // 512 blocks
    const int p   = ((bid & 7) << 6) | (bid >> 3);   // XCD-chunked remap
    const int m   = p >> 2;
    const int bte = p & 3;
    const int t = threadIdx.x;
    const int l = t & 63;
    const int w = t >> 6;              // wave: l-rows [w*32, w*32+32)
    const bool skip = (w * 32 + 32) <= m;   // entire wave in zero triangle

    const unsigned short* Fb = F + (size_t)(bte * MMAXX + m) * NLAT * (NV * 2);
    const unsigned short* wb = wt + (size_t)m * 64 * 512 + l * 8;

    const int kk = t >> 4;             // staging k (0..15; +16 second half)
    const int c8 = (t & 15) * 8;       // staging c base

    f32x4 acc[2][8];
    #pragma unroll
    for (int i = 0; i < 2; ++i)
        #pragma unroll
        for (int j = 0; j < 8; ++j) acc[i][j] = (f32x4){0.f, 0.f, 0.f, 0.f};

    // prologue: stage k-chunk 0
    {
        const bf16x8 s0 = *(const bf16x8*)(Fb + (size_t)kk * 128 + c8);
        const bf16x8 s1 = *(const bf16x8*)(Fb + (size_t)(16 + kk) * 128 + c8);
        #pragma unroll
        for (int e = 0; e < 8; ++e) {
            const int c = c8 + e;
            fs[0][c][(((kk >> 3) + (c >> 3)) & 3) * 8 + (kk & 7)]        = (unsigned short)s0[e];
            fs[0][c][((((16 + kk) >> 3) + (c >> 3)) & 3) * 8 + (kk & 7)] = (unsigned short)s1[e];
        }
    }
    __syncthreads();

    #pragma unroll
    for (int ks = 0; ks < 8; ++ks) {
        const int cur = ks & 1;
        bf16x8 s0, s1;
        if (ks < 7) {                  // issue next k-chunk loads early
            s0 = *(const bf16x8*)(Fb + ((size_t)(ks + 1) * 32 + kk) * 128 + c8);
            s1 = *(const bf16x8*)(Fb + ((size_t)(ks + 1) * 32 + 16 + kk) * 128 + c8);
        }
        if (!skip) {
            bf16x8 bq[8];
            #pragma unroll
            for (int nt = 0; nt < 8; ++nt) {
                const int c = nt * 16 + (l & 15);
                bq[nt] = *(const bf16x8*)&fs[cur][c][(((l >> 4) + (c >> 3)) & 3) * 8];
            }
            #pragma unroll
            for (int mt2 = 0; mt2 < 2; ++mt2) {
                const bf16x8 a = *(const bf16x8*)(wb + ((size_t)ks * 8 + w * 2 + mt2) * 512);
                #pragma unroll
                for (int nt = 0; nt < 8; ++nt)
                    acc[mt2][nt] = __builtin_amdgcn_mfma_f32_16x16x32_bf16(a, bq[nt], acc[mt2][nt], 0, 0, 0);
            }
        }
        if (ks < 7) {                  // write-late into other buffer
            #pragma unroll
            for (int e = 0; e < 8; ++e) {
                const int c = c8 + e;
                fs[cur ^ 1][c][(((kk >> 3) + (c >> 3)) & 3) * 8 + (kk & 7)]        = (unsigned short)s0[e];
                fs[cur ^ 1][c][((((16 + kk) >> 3) + (c >> 3)) & 3) * 8 + (kk & 7)] = (unsigned short)s1[e];
            }
        }
        __syncthreads();
    }

    // epilogue: (l_out = (w*2+mt2)*16 + (l>>4)*4 + j, c = nt*16+(l&15))
    // c<64 -> re(v=c), c>=64 -> im(v=c-64); u32 = im | re<<16.
    #pragma unroll
    for (int mt2 = 0; mt2 < 2; ++mt2) {
        const int lr = (w * 2 + mt2) * 16 + (l >> 4) * 4;
        #pragma unroll
        for (int j = 0; j < 4; ++j) {
            unsigned int* op = outu + ((size_t)(bte * LMAXX + lr + j) * MMAXX + m) * 64 + (l & 15);
            #pragma unroll
            for (int nt = 0; nt < 4; ++nt)
                op[nt * 16] = f2bf(acc[mt2][nt + 4][j]) | (f2bf(acc[mt2][nt][j]) << 16);
        }
    }
}

extern "C" void kernel_launch(void* const* d_in, const int* in_sizes, int n_in,
                              void* d_out, int out_size, void* d_ws, size_t ws_size,
                              hipStream_t stream) {
    const float* data = (const float*)d_in[0];    // [4][256][512][64] fp32
    const float* leg  = (const float*)d_in[1];    // [128][128][256] fp32
    const float* qw   = (const float*)d_in[2];    // [256] fp32
    unsigned int* outu = (unsigned int*)d_out;    // bf16 [4][128][128][64][(im,re)]

    // ws layout: tsw 256 KB | wt 8.39 MB | F(bf16) 33.6 MB
    unsigned short* tsw = (unsigned short*)d_ws;
    unsigned short* wt  = tsw + 131072;
    unsigned short* F   = wt + (size_t)4194304;

    init_tables<<<dim3(2560), 256, 0, stream>>>(leg, qw, tsw, wt);
    dft_mfma<<<dim3(NBTE * NLAT), 256, 0, stream>>>(data, tsw, F);
    leg_mfma<<<dim3(512), 256, 0, stream>>>(F, wt, outu);
}